// Round 4
// baseline (788.673 us; speedup 1.0000x reference)
//
#include <hip/hip_runtime.h>

#define N_NODES 100000
#define N_EDGES 1600000
#define D 64
#define NB 128            // edge-chunk blocks for count/scatter
#define EPB (N_EDGES / NB)   // 12500 edges per block
#define NBUCK 3125        // 100000 >> 5 buckets of 32 nodes
#define ASTRIDE 68        // padded LDS row stride (bank-conflict-free)

// -------- K1: per-block coarse counts (col-buckets and row-buckets) --------
__global__ __launch_bounds__(256) void count_kernel(const int* __restrict__ row,
                                                    const int* __restrict__ col,
                                                    int* __restrict__ matC,
                                                    int* __restrict__ matR) {
    __shared__ int cC[NBUCK];
    __shared__ int cR[NBUCK];
    int t = threadIdx.x;
    for (int j = t; j < NBUCK; j += 256) { cC[j] = 0; cR[j] = 0; }
    __syncthreads();
    int base = blockIdx.x * EPB;
    for (int i = t; i < EPB; i += 256) {
        int e = base + i;
        atomicAdd(&cC[col[e] >> 5], 1);
        atomicAdd(&cR[row[e] >> 5], 1);
    }
    __syncthreads();
    int* mc = matC + (size_t)blockIdx.x * NBUCK;
    int* mr = matR + (size_t)blockIdx.x * NBUCK;
    for (int j = t; j < NBUCK; j += 256) { mc[j] = cC[j]; mr[j] = cR[j]; }
}

// -------- K2a: per-bucket exclusive scan over the NB blocks (in place) -----
__global__ __launch_bounds__(128) void blockscan_kernel(int* __restrict__ matC,
                                                        int* __restrict__ matR,
                                                        int* __restrict__ totalsC,
                                                        int* __restrict__ totalsR) {
    int which  = blockIdx.x / NBUCK;
    int bucket = blockIdx.x % NBUCK;
    int* mat    = which ? matR : matC;
    int* totals = which ? totalsR : totalsC;
    __shared__ int lds[NB];
    int t = threadIdx.x;
    int v = mat[(size_t)t * NBUCK + bucket];
    lds[t] = v;
    __syncthreads();
    for (int off = 1; off < NB; off <<= 1) {
        int u = (t >= off) ? lds[t - off] : 0;
        __syncthreads();
        lds[t] += u;
        __syncthreads();
    }
    mat[(size_t)t * NBUCK + bucket] = (t > 0) ? lds[t - 1] : 0;
    if (t == NB - 1) totals[bucket] = lds[NB - 1];
}

// -------- K2b: exclusive scan of bucket totals (one block per array) -------
__global__ __launch_bounds__(256) void totscan_kernel(const int* __restrict__ totalsC,
                                                      int* __restrict__ bstartC,
                                                      const int* __restrict__ totalsR,
                                                      int* __restrict__ bstartR) {
    const int* tot = blockIdx.x ? totalsR : totalsC;
    int* bst       = blockIdx.x ? bstartR : bstartC;
    const int CH = (NBUCK + 255) / 256;  // 13
    __shared__ int lds[256];
    int t = threadIdx.x;
    int local[CH];
    int s = 0;
    for (int i = 0; i < CH; ++i) {
        int idx = t * CH + i;
        local[i] = (idx < NBUCK) ? tot[idx] : 0;
        s += local[i];
    }
    lds[t] = s;
    __syncthreads();
    for (int off = 1; off < 256; off <<= 1) {
        int u = (t >= off) ? lds[t - off] : 0;
        __syncthreads();
        lds[t] += u;
        __syncthreads();
    }
    int excl = (t > 0) ? lds[t - 1] : 0;
    for (int i = 0; i < CH; ++i) {
        int idx = t * CH + i;
        if (idx < NBUCK) bst[idx] = excl;
        excl += local[i];
    }
}

// -------- K3: scatter edges into bucket order, LDS cursors, NO atomics -----
// crec = (row | coloff<<17, w)   8B, col-bucket order
// rrec = (bits(w) & ~31) | (row&31)   4B, row-bucket order (w loses 5 ulp bits)
__global__ __launch_bounds__(256) void scatter_kernel(const int* __restrict__ row,
                                                      const int* __restrict__ col,
                                                      const float* __restrict__ w,
                                                      const int* __restrict__ matC,
                                                      const int* __restrict__ matR,
                                                      const int* __restrict__ bstartC,
                                                      const int* __restrict__ bstartR,
                                                      int2* __restrict__ crecs,
                                                      unsigned* __restrict__ rrecs) {
    __shared__ int cursC[NBUCK];
    __shared__ int cursR[NBUCK];
    int t = threadIdx.x;
    const int* offC = matC + (size_t)blockIdx.x * NBUCK;
    const int* offR = matR + (size_t)blockIdx.x * NBUCK;
    for (int j = t; j < NBUCK; j += 256) {
        cursC[j] = bstartC[j] + offC[j];
        cursR[j] = bstartR[j] + offR[j];
    }
    __syncthreads();
    int base = blockIdx.x * EPB;
    for (int i = t; i < EPB; i += 256) {
        int e = base + i;
        int r = row[e];
        int c = col[e];
        float we = w[e];
        int pC = atomicAdd(&cursC[c >> 5], 1);
        crecs[pC] = make_int2(r | ((c & 31) << 17), __float_as_int(we));
        int pR = atomicAdd(&cursR[r >> 5], 1);
        rrecs[pR] = (__float_as_uint(we) & ~31u) | (unsigned)(r & 31);
    }
}

// -------- K4: per row-bucket degree reduction -> dinv --------
__global__ __launch_bounds__(256) void deg_kernel(const unsigned* __restrict__ rrecs,
                                                  const int* __restrict__ bstartR,
                                                  const int* __restrict__ totalsR,
                                                  float* __restrict__ dinv) {
    __shared__ float acc[32];
    int t = threadIdx.x;
    int b = blockIdx.x;
    if (t < 32) acc[t] = 0.f;
    __syncthreads();
    int base = bstartR[b];
    int cnt  = totalsR[b];
    for (int i = t; i < cnt; i += 256) {
        unsigned v = rrecs[base + i];
        atomicAdd(&acc[v & 31u], __uint_as_float(v & ~31u));
    }
    __syncthreads();
    if (t < 32) {
        float d = acc[t];
        // d>1e-20 distinguishes a real degree (>=~6e-8) from packed-denormal junk
        dinv[b * 32 + t] = d > 1e-20f ? rsqrtf(d) : 0.f;
    }
}

// -------- K6: fused per-col-bucket gather + matmul epilogue --------
// Block = one bucket of 32 nodes. acc/xs stride 68 -> conflict-free LDS.
__global__ __launch_bounds__(256) void gather_out_kernel(
        const int2* __restrict__ crecs, const int* __restrict__ bstartC,
        const int* __restrict__ totalsC, const float* __restrict__ dinv,
        const float* __restrict__ x,
        const float* __restrict__ W0, const float* __restrict__ W1,
        const float* __restrict__ bias, float* __restrict__ out) {
    __shared__ float accL[32 * ASTRIDE];
    __shared__ float xs[32 * ASTRIDE];
    int tid = threadIdx.x;
    int b = blockIdx.x;
    int n0 = b * 32;

    for (int i = tid; i < 32 * ASTRIDE; i += 256) accL[i] = 0.f;
    // stage this bucket's 32 x-rows (used by the matmul phase)
    for (int i = tid; i < 512; i += 256) {           // 512 float4 = 32x64 floats
        int nn = i >> 4;
        int k  = (i & 15) << 2;
        *(float4*)&xs[nn * ASTRIDE + k] = *(const float4*)(x + (size_t)n0 * D + i * 4);
    }
    __syncthreads();

    int base = bstartC[b];
    int cnt  = totalsC[b];
    int g    = tid >> 4;        // 16 edge-groups
    int l16  = tid & 15;        // lane within group: owns features 4*l16..+3
    for (int k = g; k < cnt; k += 16) {
        int2 rec = crecs[base + k];
        int r       = rec.x & 0x1FFFF;
        int coloff  = ((unsigned)rec.x) >> 17;
        float we    = __int_as_float(rec.y);
        float cf    = -we * dinv[r] * dinv[n0 + coloff];
        const float4 xv = *(const float4*)(x + (size_t)r * D + l16 * 4);
        float* a = &accL[coloff * ASTRIDE + l16 * 4];
        atomicAdd(a + 0, cf * xv.x);
        atomicAdd(a + 1, cf * xv.y);
        atomicAdd(a + 2, cf * xv.z);
        atomicAdd(a + 3, cf * xv.w);
    }
    __syncthreads();

    // matmul: out[n] = xs[n]@W0 + accL[n]@W1 + b ; thread = (node, 8 j's)
    int n  = tid >> 3;
    int jl = (tid & 7) << 3;
    float4 o0 = *(const float4*)(bias + jl);
    float4 o1 = *(const float4*)(bias + jl + 4);
    for (int k = 0; k < D; k += 4) {
        float4 av = *(const float4*)&xs[n * ASTRIDE + k];
        float4 tv = *(const float4*)&accL[n * ASTRIDE + k];
        #pragma unroll
        for (int u = 0; u < 4; ++u) {
            float a = (u == 0) ? av.x : (u == 1) ? av.y : (u == 2) ? av.z : av.w;
            float t = (u == 0) ? tv.x : (u == 1) ? tv.y : (u == 2) ? tv.z : tv.w;
            const float4 w00 = *(const float4*)(W0 + (size_t)(k + u) * D + jl);
            const float4 w01 = *(const float4*)(W0 + (size_t)(k + u) * D + jl + 4);
            const float4 w10 = *(const float4*)(W1 + (size_t)(k + u) * D + jl);
            const float4 w11 = *(const float4*)(W1 + (size_t)(k + u) * D + jl + 4);
            o0.x += a * w00.x + t * w10.x;
            o0.y += a * w00.y + t * w10.y;
            o0.z += a * w00.z + t * w10.z;
            o0.w += a * w00.w + t * w10.w;
            o1.x += a * w01.x + t * w11.x;
            o1.y += a * w01.y + t * w11.y;
            o1.z += a * w01.z + t * w11.z;
            o1.w += a * w01.w + t * w11.w;
        }
    }
    float* op = out + (size_t)(n0 + n) * D + jl;
    *(float4*)op       = o0;
    *(float4*)(op + 4) = o1;
}

extern "C" void kernel_launch(void* const* d_in, const int* in_sizes, int n_in,
                              void* d_out, int out_size, void* d_ws, size_t ws_size,
                              hipStream_t stream) {
    const float* x    = (const float*)d_in[0];
    const int*   eidx = (const int*)d_in[1];   // [2, E]: row then col
    const float* ew   = (const float*)d_in[2];
    const float* W0   = (const float*)d_in[3];
    const float* W1   = (const float*)d_in[4];
    const float* b    = (const float*)d_in[5];
    float* out = (float*)d_out;

    const int* row = eidx;
    const int* col = eidx + N_EDGES;

    // Workspace layout (4B words). Everything fully overwritten each call;
    // no memset needed. Total ~5.71M words = 22.9 MB.
    int2*     crecs   = (int2*)d_ws;                           // E int2  (3.2M w)
    unsigned* rrecs   = (unsigned*)((int*)d_ws + 2 * (size_t)N_EDGES); // E (1.6M w)
    int*      matC    = (int*)rrecs + N_EDGES;                 // NB*NBUCK (400K)
    int*      matR    = matC + (size_t)NB * NBUCK;             // NB*NBUCK (400K)
    int*      totalsC = matR + (size_t)NB * NBUCK;             // NBUCK
    int*      bstartC = totalsC + NBUCK;                       // NBUCK
    int*      totalsR = bstartC + NBUCK;                       // NBUCK
    int*      bstartR = totalsR + NBUCK;                       // NBUCK
    float*    dinv    = (float*)(bstartR + NBUCK);             // N

    count_kernel    <<<NB, 256, 0, stream>>>(row, col, matC, matR);
    blockscan_kernel<<<2 * NBUCK, NB, 0, stream>>>(matC, matR, totalsC, totalsR);
    totscan_kernel  <<<2, 256, 0, stream>>>(totalsC, bstartC, totalsR, bstartR);
    scatter_kernel  <<<NB, 256, 0, stream>>>(row, col, ew, matC, matR,
                                             bstartC, bstartR, crecs, rrecs);
    deg_kernel      <<<NBUCK, 256, 0, stream>>>(rrecs, bstartR, totalsR, dinv);
    gather_out_kernel<<<NBUCK, 256, 0, stream>>>(crecs, bstartC, totalsC, dinv,
                                                 x, W0, W1, b, out);
}

// Round 5
// 337.010 us; speedup vs baseline: 2.3402x; 2.3402x over previous
//
#include <hip/hip_runtime.h>

#define N_NODES 100000
#define N_EDGES 1600000
#define D 64
#define NB 256               // edge-chunk blocks for count/scatter
#define EPB (N_EDGES / NB)   // 6250 edges per block
#define NBUCK 3125           // 100000 >> 5 buckets of 32 nodes
#define CAP 1024             // records per in-LDS sort chunk (buckets avg ~512)
#define ST 68                // padded LDS row stride (bank-conflict-free)

// -------- K1: per-block coarse counts (col-buckets and row-buckets) --------
__global__ __launch_bounds__(256) void count_kernel(const int* __restrict__ row,
                                                    const int* __restrict__ col,
                                                    int* __restrict__ matC,
                                                    int* __restrict__ matR) {
    __shared__ int cC[NBUCK];
    __shared__ int cR[NBUCK];
    int t = threadIdx.x;
    for (int j = t; j < NBUCK; j += 256) { cC[j] = 0; cR[j] = 0; }
    __syncthreads();
    int base = blockIdx.x * EPB;
    for (int i = t; i < EPB; i += 256) {
        int e = base + i;
        atomicAdd(&cC[col[e] >> 5], 1);
        atomicAdd(&cR[row[e] >> 5], 1);
    }
    __syncthreads();
    int* mc = matC + (size_t)blockIdx.x * NBUCK;
    int* mr = matR + (size_t)blockIdx.x * NBUCK;
    for (int j = t; j < NBUCK; j += 256) { mc[j] = cC[j]; mr[j] = cR[j]; }
}

// -------- K2a: per-bucket exclusive scan over the NB blocks (in place) -----
__global__ __launch_bounds__(NB) void blockscan_kernel(int* __restrict__ matC,
                                                       int* __restrict__ matR,
                                                       int* __restrict__ totalsC,
                                                       int* __restrict__ totalsR) {
    int which  = blockIdx.x / NBUCK;
    int bucket = blockIdx.x % NBUCK;
    int* mat    = which ? matR : matC;
    int* totals = which ? totalsR : totalsC;
    __shared__ int lds[NB];
    int t = threadIdx.x;
    int v = mat[(size_t)t * NBUCK + bucket];
    lds[t] = v;
    __syncthreads();
    for (int off = 1; off < NB; off <<= 1) {
        int u = (t >= off) ? lds[t - off] : 0;
        __syncthreads();
        lds[t] += u;
        __syncthreads();
    }
    mat[(size_t)t * NBUCK + bucket] = (t > 0) ? lds[t - 1] : 0;
    if (t == NB - 1) totals[bucket] = lds[NB - 1];
}

// -------- K2b: exclusive scan of bucket totals (one block per array) -------
__global__ __launch_bounds__(256) void totscan_kernel(const int* __restrict__ totalsC,
                                                      int* __restrict__ bstartC,
                                                      const int* __restrict__ totalsR,
                                                      int* __restrict__ bstartR) {
    const int* tot = blockIdx.x ? totalsR : totalsC;
    int* bst       = blockIdx.x ? bstartR : bstartC;
    const int CH = (NBUCK + 255) / 256;  // 13
    __shared__ int lds[256];
    int t = threadIdx.x;
    int local[CH];
    int s = 0;
    for (int i = 0; i < CH; ++i) {
        int idx = t * CH + i;
        local[i] = (idx < NBUCK) ? tot[idx] : 0;
        s += local[i];
    }
    lds[t] = s;
    __syncthreads();
    for (int off = 1; off < 256; off <<= 1) {
        int u = (t >= off) ? lds[t - off] : 0;
        __syncthreads();
        lds[t] += u;
        __syncthreads();
    }
    int excl = (t > 0) ? lds[t - 1] : 0;
    for (int i = 0; i < CH; ++i) {
        int idx = t * CH + i;
        if (idx < NBUCK) bst[idx] = excl;
        excl += local[i];
    }
}

// -------- K3: scatter edges into bucket order, LDS cursors, NO globals -----
// crec = (row | coloff<<17, w)   8B, col-bucket order
// rrec = (bits(w) & ~31) | (row&31)   4B, row-bucket order (w loses 5 ulp bits)
__global__ __launch_bounds__(256) void scatter_kernel(const int* __restrict__ row,
                                                      const int* __restrict__ col,
                                                      const float* __restrict__ w,
                                                      const int* __restrict__ matC,
                                                      const int* __restrict__ matR,
                                                      const int* __restrict__ bstartC,
                                                      const int* __restrict__ bstartR,
                                                      int2* __restrict__ crecs,
                                                      unsigned* __restrict__ rrecs) {
    __shared__ int cursC[NBUCK];
    __shared__ int cursR[NBUCK];
    int t = threadIdx.x;
    const int* offC = matC + (size_t)blockIdx.x * NBUCK;
    const int* offR = matR + (size_t)blockIdx.x * NBUCK;
    for (int j = t; j < NBUCK; j += 256) {
        cursC[j] = bstartC[j] + offC[j];
        cursR[j] = bstartR[j] + offR[j];
    }
    __syncthreads();
    int base = blockIdx.x * EPB;
    for (int i = t; i < EPB; i += 256) {
        int e = base + i;
        int r = row[e];
        int c = col[e];
        float we = w[e];
        int pC = atomicAdd(&cursC[c >> 5], 1);
        crecs[pC] = make_int2(r | ((c & 31) << 17), __float_as_int(we));
        int pR = atomicAdd(&cursR[r >> 5], 1);
        rrecs[pR] = (__float_as_uint(we) & ~31u) | (unsigned)(r & 31);
    }
}

// -------- K4: per row-bucket degree reduction -> dinv --------
__global__ __launch_bounds__(256) void deg_kernel(const unsigned* __restrict__ rrecs,
                                                  const int* __restrict__ bstartR,
                                                  const int* __restrict__ totalsR,
                                                  float* __restrict__ dinv) {
    __shared__ float acc[32];
    int t = threadIdx.x;
    int b = blockIdx.x;
    if (t < 32) acc[t] = 0.f;
    __syncthreads();
    int base = bstartR[b];
    int cnt  = totalsR[b];
    for (int i = t; i < cnt; i += 256) {
        unsigned v = rrecs[base + i];
        atomicAdd(&acc[v & 31u], __uint_as_float(v & ~31u));
    }
    __syncthreads();
    if (t < 32) {
        float d = acc[t];
        dinv[b * 32 + t] = d > 0.f ? rsqrtf(d) : 0.f;
    }
}

// -------- K5: fused exact-col sort + register gather + matmul --------
// Block = one bucket of 32 nodes; 256 threads = 32 node-groups x 8 lanes.
// Phase A (per CAP-chunk): LDS counting sort of records by coloff.
// Phase B: each node-group walks ITS contiguous list, float4x2 register acc.
// Phase C: out = x@W0 + Tx1@W1 + b, xs/ts in LDS (stride 68, conflict-free).
__global__ __launch_bounds__(256) void gather_out_kernel(
        const int2* __restrict__ crecs, const int* __restrict__ bstartC,
        const int* __restrict__ totalsC, const float* __restrict__ dinv,
        const float* __restrict__ x,
        const float* __restrict__ W0, const float* __restrict__ W1,
        const float* __restrict__ bias, float* __restrict__ out) {
    __shared__ __align__(16) char smem[32 * ST * 4 * 2];   // 17408 B
    int2* raw = (int2*)smem;                 // [0, 8192)     gather phase
    int2* srt = (int2*)(smem + 8192);        // [8192, 16384) gather phase
    int*  cnt32   = (int*)(smem + 16384);    // 32
    int*  start32 = cnt32 + 32;              // 32
    int*  cur32   = cnt32 + 64;              // 32
    float* xs = (float*)smem;                // [0, 8704)     matmul phase
    float* ts = (float*)(smem + 32 * ST * 4);// [8704, 17408) matmul phase

    int tid = threadIdx.x;
    int b   = blockIdx.x;
    int n0  = b * 32;
    int n   = tid >> 3;      // node within bucket
    int j   = tid & 7;       // lane owns features 8j..8j+7

    int base = bstartC[b];
    int cnt  = totalsC[b];

    float4 acc0 = make_float4(0.f, 0.f, 0.f, 0.f);
    float4 acc1 = make_float4(0.f, 0.f, 0.f, 0.f);
    const float* xj = x + (size_t)(j << 3);

    for (int cb = 0; cb < cnt; cb += CAP) {
        int m = min(CAP, cnt - cb);
        if (tid < 32) cnt32[tid] = 0;
        __syncthreads();
        for (int i = tid; i < m; i += 256) {
            int2 rec = crecs[base + cb + i];
            raw[i] = rec;
            atomicAdd(&cnt32[((unsigned)rec.x) >> 17], 1);
        }
        __syncthreads();
        if (tid == 0) {
            int s = 0;
            for (int k = 0; k < 32; ++k) {
                int v = cnt32[k]; start32[k] = s; cur32[k] = s; s += v;
            }
        }
        __syncthreads();
        for (int i = tid; i < m; i += 256) {
            int2 rec = raw[i];
            int p = atomicAdd(&cur32[((unsigned)rec.x) >> 17], 1);
            srt[p] = rec;
        }
        __syncthreads();
        int ks = start32[n];
        int ke = ks + cnt32[n];
        int k = ks;
        for (; k + 1 < ke; k += 2) {
            int2 ra = srt[k];
            int2 rb = srt[k + 1];
            int r0 = ra.x & 0x1FFFF;
            int r1 = rb.x & 0x1FFFF;
            float c0 = __int_as_float(ra.y) * dinv[r0];
            float c1 = __int_as_float(rb.y) * dinv[r1];
            const float* p0 = xj + (size_t)r0 * D;
            const float* p1 = xj + (size_t)r1 * D;
            float4 a0 = *(const float4*)p0;
            float4 a1 = *(const float4*)(p0 + 4);
            float4 b0 = *(const float4*)p1;
            float4 b1 = *(const float4*)(p1 + 4);
            acc0.x += c0 * a0.x; acc0.y += c0 * a0.y; acc0.z += c0 * a0.z; acc0.w += c0 * a0.w;
            acc1.x += c0 * a1.x; acc1.y += c0 * a1.y; acc1.z += c0 * a1.z; acc1.w += c0 * a1.w;
            acc0.x += c1 * b0.x; acc0.y += c1 * b0.y; acc0.z += c1 * b0.z; acc0.w += c1 * b0.w;
            acc1.x += c1 * b1.x; acc1.y += c1 * b1.y; acc1.z += c1 * b1.z; acc1.w += c1 * b1.w;
        }
        if (k < ke) {
            int2 ra = srt[k];
            int r0 = ra.x & 0x1FFFF;
            float c0 = __int_as_float(ra.y) * dinv[r0];
            const float* p0 = xj + (size_t)r0 * D;
            float4 a0 = *(const float4*)p0;
            float4 a1 = *(const float4*)(p0 + 4);
            acc0.x += c0 * a0.x; acc0.y += c0 * a0.y; acc0.z += c0 * a0.z; acc0.w += c0 * a0.w;
            acc1.x += c0 * a1.x; acc1.y += c0 * a1.y; acc1.z += c0 * a1.z; acc1.w += c0 * a1.w;
        }
        __syncthreads();   // srt reads done before next chunk / smem reuse
    }

    // Phase C: write ts = -dinv[n]*acc, stage xs, then matmul epilogue.
    float dn = -dinv[n0 + n];
    float* tp = ts + n * ST + (j << 3);
    *(float4*)tp       = make_float4(dn * acc0.x, dn * acc0.y, dn * acc0.z, dn * acc0.w);
    *(float4*)(tp + 4) = make_float4(dn * acc1.x, dn * acc1.y, dn * acc1.z, dn * acc1.w);
    for (int i = tid; i < 512; i += 256) {          // 512 float4 = 32x64 floats
        int nn = i >> 4;
        int kk = (i & 15) << 2;
        *(float4*)&xs[nn * ST + kk] = *(const float4*)(x + (size_t)n0 * D + i * 4);
    }
    __syncthreads();

    int jl = j << 3;
    float4 o0 = *(const float4*)(bias + jl);
    float4 o1 = *(const float4*)(bias + jl + 4);
    for (int k = 0; k < D; k += 4) {
        float4 av = *(const float4*)&xs[n * ST + k];
        float4 tv = *(const float4*)&ts[n * ST + k];
        #pragma unroll
        for (int u = 0; u < 4; ++u) {
            float a = (u == 0) ? av.x : (u == 1) ? av.y : (u == 2) ? av.z : av.w;
            float t = (u == 0) ? tv.x : (u == 1) ? tv.y : (u == 2) ? tv.z : tv.w;
            const float4 w00 = *(const float4*)(W0 + (size_t)(k + u) * D + jl);
            const float4 w01 = *(const float4*)(W0 + (size_t)(k + u) * D + jl + 4);
            const float4 w10 = *(const float4*)(W1 + (size_t)(k + u) * D + jl);
            const float4 w11 = *(const float4*)(W1 + (size_t)(k + u) * D + jl + 4);
            o0.x += a * w00.x + t * w10.x;
            o0.y += a * w00.y + t * w10.y;
            o0.z += a * w00.z + t * w10.z;
            o0.w += a * w00.w + t * w10.w;
            o1.x += a * w01.x + t * w11.x;
            o1.y += a * w01.y + t * w11.y;
            o1.z += a * w01.z + t * w11.z;
            o1.w += a * w01.w + t * w11.w;
        }
    }
    float* op = out + (size_t)(n0 + n) * D + jl;
    *(float4*)op       = o0;
    *(float4*)(op + 4) = o1;
}

extern "C" void kernel_launch(void* const* d_in, const int* in_sizes, int n_in,
                              void* d_out, int out_size, void* d_ws, size_t ws_size,
                              hipStream_t stream) {
    const float* x    = (const float*)d_in[0];
    const int*   eidx = (const int*)d_in[1];   // [2, E]: row then col
    const float* ew   = (const float*)d_in[2];
    const float* W0   = (const float*)d_in[3];
    const float* W1   = (const float*)d_in[4];
    const float* b    = (const float*)d_in[5];
    float* out = (float*)d_out;

    const int* row = eidx;
    const int* col = eidx + N_EDGES;

    // Workspace layout (4B words), fully overwritten each call, no memset.
    // crecs 12.8MB + rrecs 6.4MB + matC/matR 3.2MB*2 + small + dinv ~= 26.3MB
    int2*     crecs   = (int2*)d_ws;                                   // E int2
    unsigned* rrecs   = (unsigned*)((int*)d_ws + 2 * (size_t)N_EDGES); // E
    int*      matC    = (int*)rrecs + N_EDGES;                         // NB*NBUCK
    int*      matR    = matC + (size_t)NB * NBUCK;                     // NB*NBUCK
    int*      totalsC = matR + (size_t)NB * NBUCK;                     // NBUCK
    int*      bstartC = totalsC + NBUCK;                               // NBUCK
    int*      totalsR = bstartC + NBUCK;                               // NBUCK
    int*      bstartR = totalsR + NBUCK;                               // NBUCK
    float*    dinv    = (float*)(bstartR + NBUCK);                     // N

    count_kernel     <<<NB, 256, 0, stream>>>(row, col, matC, matR);
    blockscan_kernel <<<2 * NBUCK, NB, 0, stream>>>(matC, matR, totalsC, totalsR);
    totscan_kernel   <<<2, 256, 0, stream>>>(totalsC, bstartC, totalsR, bstartR);
    scatter_kernel   <<<NB, 256, 0, stream>>>(row, col, ew, matC, matR,
                                              bstartC, bstartR, crecs, rrecs);
    deg_kernel       <<<NBUCK, 256, 0, stream>>>(rrecs, bstartR, totalsR, dinv);
    gather_out_kernel<<<NBUCK, 256, 0, stream>>>(crecs, bstartC, totalsC, dinv,
                                                 x, W0, W1, b, out);
}

// Round 6
// 292.479 us; speedup vs baseline: 2.6965x; 1.1523x over previous
//
#include <hip/hip_runtime.h>

#define N_NODES 100000
#define N_EDGES 1600000
#define D 64
#define NB 128               // edge-chunk blocks for count/scatter
#define EPB (N_EDGES / NB)   // 12500 edges per block
#define NBUCK 3125           // 100000 >> 5 buckets of 32 nodes
#define NBUCK_PAD 3136       // 32-multiple padding (98 groups of 32)
#define NGRP 98              // NBUCK_PAD / 32
#define CAP 1024             // records per in-LDS sort chunk (buckets avg ~512)
#define ST 68                // padded LDS row stride (bank-conflict-free)

// -------- K1: per-block coarse counts (col-buckets and row-buckets) --------
__global__ __launch_bounds__(512) void count_kernel(const int* __restrict__ row,
                                                    const int* __restrict__ col,
                                                    int* __restrict__ matC,
                                                    int* __restrict__ matR) {
    __shared__ int cC[NBUCK_PAD];
    __shared__ int cR[NBUCK_PAD];
    int t = threadIdx.x;
    for (int j = t; j < NBUCK_PAD; j += 512) { cC[j] = 0; cR[j] = 0; }
    __syncthreads();
    int base = blockIdx.x * EPB;
    for (int i = t; i < EPB; i += 512) {
        int e = base + i;
        atomicAdd(&cC[col[e] >> 5], 1);
        atomicAdd(&cR[row[e] >> 5], 1);
    }
    __syncthreads();
    int* mc = matC + (size_t)blockIdx.x * NBUCK_PAD;
    int* mr = matR + (size_t)blockIdx.x * NBUCK_PAD;
    for (int j = t; j < NBUCK_PAD; j += 512) { mc[j] = cC[j]; mr[j] = cR[j]; }
}

// -------- K2a: tiled per-bucket exclusive scan over NB blocks (in place) ---
// Block handles 32 buckets; loads a [128 x 32] tile coalesced (int4),
// scans each bucket with an 8-lane shfl group.
__global__ __launch_bounds__(256) void blockscan_kernel(int* __restrict__ matC,
                                                        int* __restrict__ matR,
                                                        int* __restrict__ totalsC,
                                                        int* __restrict__ totalsR) {
    int which = blockIdx.x / NGRP;
    int grp   = blockIdx.x % NGRP;
    int* mat    = which ? matR : matC;
    int* totals = which ? totalsR : totalsC;
    int j0 = grp * 32;
    __shared__ int tile[NB][33];
    int t = threadIdx.x;
    int r = t >> 1;          // 0..127
    int h = t & 1;           // 0..1
    {
        const int* src = mat + (size_t)r * NBUCK_PAD + j0 + h * 16;
        int4 v0 = *(const int4*)(src + 0);
        int4 v1 = *(const int4*)(src + 4);
        int4 v2 = *(const int4*)(src + 8);
        int4 v3 = *(const int4*)(src + 12);
        int cb = h * 16;
        tile[r][cb+0]=v0.x;  tile[r][cb+1]=v0.y;  tile[r][cb+2]=v0.z;  tile[r][cb+3]=v0.w;
        tile[r][cb+4]=v1.x;  tile[r][cb+5]=v1.y;  tile[r][cb+6]=v1.z;  tile[r][cb+7]=v1.w;
        tile[r][cb+8]=v2.x;  tile[r][cb+9]=v2.y;  tile[r][cb+10]=v2.z; tile[r][cb+11]=v2.w;
        tile[r][cb+12]=v3.x; tile[r][cb+13]=v3.y; tile[r][cb+14]=v3.z; tile[r][cb+15]=v3.w;
    }
    __syncthreads();
    int g = t >> 3;          // bucket within tile, 0..31
    int l = t & 7;           // lane in 8-wide scan group
    int rows0 = l * 16;
    int vals[16];
    int s = 0;
    #pragma unroll
    for (int i = 0; i < 16; ++i) { vals[i] = tile[rows0 + i][g]; s += vals[i]; }
    int inc = s;
    #pragma unroll
    for (int d = 1; d < 8; d <<= 1) {
        int u = __shfl_up(inc, d, 8);
        if (l >= d) inc += u;
    }
    int excl = inc - s;
    #pragma unroll
    for (int i = 0; i < 16; ++i) { int e2 = excl; excl += vals[i]; tile[rows0 + i][g] = e2; }
    if (l == 7) totals[j0 + g] = inc;
    __syncthreads();
    {
        int* dst = mat + (size_t)r * NBUCK_PAD + j0 + h * 16;
        int cb = h * 16;
        int4 v0 = make_int4(tile[r][cb+0],  tile[r][cb+1],  tile[r][cb+2],  tile[r][cb+3]);
        int4 v1 = make_int4(tile[r][cb+4],  tile[r][cb+5],  tile[r][cb+6],  tile[r][cb+7]);
        int4 v2 = make_int4(tile[r][cb+8],  tile[r][cb+9],  tile[r][cb+10], tile[r][cb+11]);
        int4 v3 = make_int4(tile[r][cb+12], tile[r][cb+13], tile[r][cb+14], tile[r][cb+15]);
        *(int4*)(dst + 0)  = v0;
        *(int4*)(dst + 4)  = v1;
        *(int4*)(dst + 8)  = v2;
        *(int4*)(dst + 12) = v3;
    }
}

// -------- K2b: exclusive scan of bucket totals (one block per array) -------
__global__ __launch_bounds__(256) void totscan_kernel(const int* __restrict__ totalsC,
                                                      int* __restrict__ bstartC,
                                                      const int* __restrict__ totalsR,
                                                      int* __restrict__ bstartR) {
    const int* tot = blockIdx.x ? totalsR : totalsC;
    int* bst       = blockIdx.x ? bstartR : bstartC;
    const int CH = (NBUCK_PAD + 255) / 256;  // 13
    __shared__ int lds[256];
    int t = threadIdx.x;
    int local[CH];
    int s = 0;
    for (int i = 0; i < CH; ++i) {
        int idx = t * CH + i;
        local[i] = (idx < NBUCK_PAD) ? tot[idx] : 0;
        s += local[i];
    }
    lds[t] = s;
    __syncthreads();
    for (int off = 1; off < 256; off <<= 1) {
        int u = (t >= off) ? lds[t - off] : 0;
        __syncthreads();
        lds[t] += u;
        __syncthreads();
    }
    int excl = (t > 0) ? lds[t - 1] : 0;
    for (int i = 0; i < CH; ++i) {
        int idx = t * CH + i;
        if (idx < NBUCK_PAD) bst[idx] = excl;
        excl += local[i];
    }
}

// -------- K3: scatter edges into bucket order, LDS cursors, NO globals -----
// crec = (row | coloff<<17, w)   8B, col-bucket order
// rrec = (bits(w) & ~31) | (row&31)   4B, row-bucket order (w loses 5 ulp bits)
__global__ __launch_bounds__(512) void scatter_kernel(const int* __restrict__ row,
                                                      const int* __restrict__ col,
                                                      const float* __restrict__ w,
                                                      const int* __restrict__ matC,
                                                      const int* __restrict__ matR,
                                                      const int* __restrict__ bstartC,
                                                      const int* __restrict__ bstartR,
                                                      int2* __restrict__ crecs,
                                                      unsigned* __restrict__ rrecs) {
    __shared__ int cursC[NBUCK];
    __shared__ int cursR[NBUCK];
    int t = threadIdx.x;
    const int* offC = matC + (size_t)blockIdx.x * NBUCK_PAD;
    const int* offR = matR + (size_t)blockIdx.x * NBUCK_PAD;
    for (int j = t; j < NBUCK; j += 512) {
        cursC[j] = bstartC[j] + offC[j];
        cursR[j] = bstartR[j] + offR[j];
    }
    __syncthreads();
    int base = blockIdx.x * EPB;
    for (int i = t; i < EPB; i += 512) {
        int e = base + i;
        int r = row[e];
        int c = col[e];
        float we = w[e];
        int pC = atomicAdd(&cursC[c >> 5], 1);
        crecs[pC] = make_int2(r | ((c & 31) << 17), __float_as_int(we));
        int pR = atomicAdd(&cursR[r >> 5], 1);
        rrecs[pR] = (__float_as_uint(we) & ~31u) | (unsigned)(r & 31);
    }
}

// -------- K4: per row-bucket degree reduction -> dinv --------
__global__ __launch_bounds__(256) void deg_kernel(const unsigned* __restrict__ rrecs,
                                                  const int* __restrict__ bstartR,
                                                  const int* __restrict__ totalsR,
                                                  float* __restrict__ dinv) {
    __shared__ float acc[32];
    int t = threadIdx.x;
    int b = blockIdx.x;
    if (t < 32) acc[t] = 0.f;
    __syncthreads();
    int base = bstartR[b];
    int cnt  = totalsR[b];
    for (int i = t; i < cnt; i += 256) {
        unsigned v = rrecs[base + i];
        atomicAdd(&acc[v & 31u], __uint_as_float(v & ~31u));
    }
    __syncthreads();
    if (t < 32) {
        float d = acc[t];
        dinv[b * 32 + t] = d > 0.f ? rsqrtf(d) : 0.f;
    }
}

#define FMA8(cc, av, bv)                                                       \
    acc0.x += cc * av.x; acc0.y += cc * av.y; acc0.z += cc * av.z; acc0.w += cc * av.w; \
    acc1.x += cc * bv.x; acc1.y += cc * bv.y; acc1.z += cc * bv.z; acc1.w += cc * bv.w;

// -------- K5: fused exact-col sort + register gather + matmul --------
// Block = one bucket of 32 nodes; 256 threads = 32 node-groups x 8 lanes.
// dinv[r] is folded into the record weight during the sort's load phase.
__global__ __launch_bounds__(256) void gather_out_kernel(
        const int2* __restrict__ crecs, const int* __restrict__ bstartC,
        const int* __restrict__ totalsC, const float* __restrict__ dinv,
        const float* __restrict__ x,
        const float* __restrict__ W0, const float* __restrict__ W1,
        const float* __restrict__ bias, float* __restrict__ out) {
    __shared__ __align__(16) char smem[32 * ST * 4 * 2];   // 17408 B
    int2* raw = (int2*)smem;                 // [0, 8192)     gather phase
    int2* srt = (int2*)(smem + 8192);        // [8192, 16384) gather phase
    int*  cnt32   = (int*)(smem + 16384);    // 32
    int*  start32 = cnt32 + 32;              // 32
    int*  cur32   = cnt32 + 64;              // 32
    float* xs = (float*)smem;                // [0, 8704)     matmul phase
    float* ts = (float*)(smem + 32 * ST * 4);// [8704, 17408) matmul phase

    int tid = threadIdx.x;
    int b   = blockIdx.x;
    int n0  = b * 32;
    int n   = tid >> 3;      // node within bucket
    int j   = tid & 7;       // lane owns features 8j..8j+7

    int base = bstartC[b];
    int cnt  = totalsC[b];

    float4 acc0 = make_float4(0.f, 0.f, 0.f, 0.f);
    float4 acc1 = make_float4(0.f, 0.f, 0.f, 0.f);
    const float* xj = x + (size_t)(j << 3);

    for (int cb = 0; cb < cnt; cb += CAP) {
        int m = min(CAP, cnt - cb);
        if (tid < 32) cnt32[tid] = 0;
        __syncthreads();
        for (int i = tid; i < m; i += 256) {
            int2 rec = crecs[base + cb + i];
            int r = rec.x & 0x1FFFF;
            rec.y = __float_as_int(__int_as_float(rec.y) * dinv[r]);
            raw[i] = rec;
            atomicAdd(&cnt32[((unsigned)rec.x) >> 17], 1);
        }
        __syncthreads();
        if (tid < 32) {               // wave 0, lanes 0..31: shfl scan
            int v = cnt32[tid];
            int inc = v;
            #pragma unroll
            for (int d = 1; d < 32; d <<= 1) {
                int u = __shfl_up(inc, d, 32);
                if (tid >= d) inc += u;
            }
            start32[tid] = inc - v;
            cur32[tid]   = inc - v;
        }
        __syncthreads();
        for (int i = tid; i < m; i += 256) {
            int2 rec = raw[i];
            int p = atomicAdd(&cur32[((unsigned)rec.x) >> 17], 1);
            srt[p] = rec;
        }
        __syncthreads();
        int ks = start32[n];
        int ke = ks + cnt32[n];
        int k = ks;
        for (; k + 3 < ke; k += 4) {
            int2 e0 = srt[k + 0];
            int2 e1 = srt[k + 1];
            int2 e2 = srt[k + 2];
            int2 e3 = srt[k + 3];
            const float* p0 = xj + (size_t)(e0.x & 0x1FFFF) * D;
            const float* p1 = xj + (size_t)(e1.x & 0x1FFFF) * D;
            const float* p2 = xj + (size_t)(e2.x & 0x1FFFF) * D;
            const float* p3 = xj + (size_t)(e3.x & 0x1FFFF) * D;
            float c0 = __int_as_float(e0.y);
            float c1 = __int_as_float(e1.y);
            float c2 = __int_as_float(e2.y);
            float c3 = __int_as_float(e3.y);
            float4 a0 = *(const float4*)p0, b0 = *(const float4*)(p0 + 4);
            float4 a1 = *(const float4*)p1, b1 = *(const float4*)(p1 + 4);
            float4 a2 = *(const float4*)p2, b2 = *(const float4*)(p2 + 4);
            float4 a3 = *(const float4*)p3, b3 = *(const float4*)(p3 + 4);
            FMA8(c0, a0, b0)
            FMA8(c1, a1, b1)
            FMA8(c2, a2, b2)
            FMA8(c3, a3, b3)
        }
        for (; k < ke; ++k) {
            int2 e0 = srt[k];
            const float* p0 = xj + (size_t)(e0.x & 0x1FFFF) * D;
            float c0 = __int_as_float(e0.y);
            float4 a0 = *(const float4*)p0, b0 = *(const float4*)(p0 + 4);
            FMA8(c0, a0, b0)
        }
        __syncthreads();   // srt reads done before next chunk / smem reuse
    }

    // Phase C: write ts = -dinv[n]*acc, stage xs, then matmul epilogue.
    float dn = -dinv[n0 + n];
    float* tp = ts + n * ST + (j << 3);
    *(float4*)tp       = make_float4(dn * acc0.x, dn * acc0.y, dn * acc0.z, dn * acc0.w);
    *(float4*)(tp + 4) = make_float4(dn * acc1.x, dn * acc1.y, dn * acc1.z, dn * acc1.w);
    for (int i = tid; i < 512; i += 256) {          // 512 float4 = 32x64 floats
        int nn = i >> 4;
        int kk = (i & 15) << 2;
        *(float4*)&xs[nn * ST + kk] = *(const float4*)(x + (size_t)n0 * D + i * 4);
    }
    __syncthreads();

    int jl = j << 3;
    float4 o0 = *(const float4*)(bias + jl);
    float4 o1 = *(const float4*)(bias + jl + 4);
    for (int k = 0; k < D; k += 4) {
        float4 av = *(const float4*)&xs[n * ST + k];
        float4 tv = *(const float4*)&ts[n * ST + k];
        #pragma unroll
        for (int u = 0; u < 4; ++u) {
            float a = (u == 0) ? av.x : (u == 1) ? av.y : (u == 2) ? av.z : av.w;
            float t = (u == 0) ? tv.x : (u == 1) ? tv.y : (u == 2) ? tv.z : tv.w;
            const float4 w00 = *(const float4*)(W0 + (size_t)(k + u) * D + jl);
            const float4 w01 = *(const float4*)(W0 + (size_t)(k + u) * D + jl + 4);
            const float4 w10 = *(const float4*)(W1 + (size_t)(k + u) * D + jl);
            const float4 w11 = *(const float4*)(W1 + (size_t)(k + u) * D + jl + 4);
            o0.x += a * w00.x + t * w10.x;
            o0.y += a * w00.y + t * w10.y;
            o0.z += a * w00.z + t * w10.z;
            o0.w += a * w00.w + t * w10.w;
            o1.x += a * w01.x + t * w11.x;
            o1.y += a * w01.y + t * w11.y;
            o1.z += a * w01.z + t * w11.z;
            o1.w += a * w01.w + t * w11.w;
        }
    }
    float* op = out + (size_t)(n0 + n) * D + jl;
    *(float4*)op       = o0;
    *(float4*)(op + 4) = o1;
}

extern "C" void kernel_launch(void* const* d_in, const int* in_sizes, int n_in,
                              void* d_out, int out_size, void* d_ws, size_t ws_size,
                              hipStream_t stream) {
    const float* x    = (const float*)d_in[0];
    const int*   eidx = (const int*)d_in[1];   // [2, E]: row then col
    const float* ew   = (const float*)d_in[2];
    const float* W0   = (const float*)d_in[3];
    const float* W1   = (const float*)d_in[4];
    const float* b    = (const float*)d_in[5];
    float* out = (float*)d_out;

    const int* row = eidx;
    const int* col = eidx + N_EDGES;

    // Workspace layout (4B words), fully overwritten each call, no memset.
    int2*     crecs   = (int2*)d_ws;                                   // E int2
    unsigned* rrecs   = (unsigned*)((int*)d_ws + 2 * (size_t)N_EDGES); // E
    int*      matC    = (int*)rrecs + N_EDGES;                         // NB*NBUCK_PAD
    int*      matR    = matC + (size_t)NB * NBUCK_PAD;                 // NB*NBUCK_PAD
    int*      totalsC = matR + (size_t)NB * NBUCK_PAD;                 // NBUCK_PAD
    int*      bstartC = totalsC + NBUCK_PAD;                           // NBUCK_PAD
    int*      totalsR = bstartC + NBUCK_PAD;                           // NBUCK_PAD
    int*      bstartR = totalsR + NBUCK_PAD;                           // NBUCK_PAD
    float*    dinv    = (float*)(bstartR + NBUCK_PAD);                 // N

    count_kernel     <<<NB, 512, 0, stream>>>(row, col, matC, matR);
    blockscan_kernel <<<2 * NGRP, 256, 0, stream>>>(matC, matR, totalsC, totalsR);
    totscan_kernel   <<<2, 256, 0, stream>>>(totalsC, bstartC, totalsR, bstartR);
    scatter_kernel   <<<NB, 512, 0, stream>>>(row, col, ew, matC, matR,
                                              bstartC, bstartR, crecs, rrecs);
    deg_kernel       <<<NBUCK, 256, 0, stream>>>(rrecs, bstartR, totalsR, dinv);
    gather_out_kernel<<<NBUCK, 256, 0, stream>>>(crecs, bstartC, totalsC, dinv,
                                                 x, W0, W1, b, out);
}